// Round 13
// baseline (296.444 us; speedup 1.0000x reference)
//
#include <hip/hip_runtime.h>
#include <hip/hip_bf16.h>
#include <stdint.h>

#define B_ 4
#define T_ 2048
#define S_ 512
#define HID_ 2048
#define ND_ 1024
#define NH_ 16
#define HD_ 128

typedef unsigned short u16;
typedef unsigned int u32;
typedef __attribute__((ext_vector_type(8))) short bf16x8;
typedef __attribute__((ext_vector_type(4))) float f32x4;
typedef __attribute__((ext_vector_type(16))) float f32x16;
typedef __attribute__((ext_vector_type(4))) float f4;
typedef __attribute__((ext_vector_type(4))) u16 us4;
typedef __attribute__((ext_vector_type(8))) u16 us8;
typedef __attribute__((ext_vector_type(4))) u32 u32x4;

__device__ inline u16 f2bf(float f) {
  unsigned u = __builtin_bit_cast(unsigned, f);
  u += 0x7FFFu + ((u >> 16) & 1u);   // round-to-nearest-even
  return (u16)(u >> 16);
}

__device__ inline u32 cvtpk(float lo, float hi) {   // bf16(lo) | bf16(hi)<<16
  u32 r;
  asm("v_cvt_pk_bf16_f32 %0, %1, %2" : "=v"(r) : "v"(lo), "v"(hi));
  return r;
}

__device__ inline f32x4 mfma16(bf16x8 a, bf16x8 b, f32x4 c) {
  return __builtin_amdgcn_mfma_f32_16x16x32_bf16(a, b, c, 0, 0, 0);
}
__device__ inline f32x16 mfma32(bf16x8 a, bf16x8 b, f32x16 c) {
  return __builtin_amdgcn_mfma_f32_32x32x16_bf16(a, b, c, 0, 0, 0);
}

__device__ inline void gload_lds16(const u16* g, u16* l) {
  __builtin_amdgcn_global_load_lds(
      (const __attribute__((address_space(1))) unsigned int*)g,
      (__attribute__((address_space(3))) unsigned int*)l, 16, 0, 0);
}

// fenced barrier: s_barrier that is ALSO a compiler memory fence (R10 race fix)
#define FENCED_BARRIER() asm volatile("s_barrier" ::: "memory")

// ---------------- fp32 -> bf16 conversion for all operands ----------------
__global__ __launch_bounds__(256) void convert_all(
    const float* __restrict__ h, const float* __restrict__ n,
    const float* __restrict__ qw, const float* __restrict__ kw,
    const float* __restrict__ vw, const float* __restrict__ ow,
    u16* __restrict__ dh, u16* __restrict__ dn, u16* __restrict__ dqw,
    u16* __restrict__ dkw, u16* __restrict__ dvw, u16* __restrict__ dow) {
  const int C0 = 4194304;            // hidden 16.78M
  const int C1 = C0 + 524288;        // notes 2.10M
  const int C2 = C1 + 1048576;       // q_w 4.19M
  const int C3 = C2 + 524288;        // k_w 2.10M
  const int C4 = C3 + 524288;        // v_w 2.10M
  const int C5 = C4 + 1048576;       // o_w 4.19M
  for (int c = blockIdx.x * blockDim.x + threadIdx.x; c < C5;
       c += gridDim.x * blockDim.x) {
    const float* s; u16* d; int o;
    if (c < C0)      { s = h;  d = dh;  o = c; }
    else if (c < C1) { s = n;  d = dn;  o = c - C0; }
    else if (c < C2) { s = qw; d = dqw; o = c - C1; }
    else if (c < C3) { s = kw; d = dkw; o = c - C2; }
    else if (c < C4) { s = vw; d = dvw; o = c - C3; }
    else             { s = ow; d = dow; o = c - C4; }
    f4 v = ((const f4*)s)[o];
    us4 r = { f2bf(v[0]), f2bf(v[1]), f2bf(v[2]), f2bf(v[3]) };
    ((us4*)d)[o] = r;
  }
}

// ---------------- small GEMM (128^2 tile, m97 structure) ----------------
template <bool OUT_BF16>
__global__ __launch_bounds__(256) void gemm_bt(
    const u16* __restrict__ A, const u16* __restrict__ Bm,
    const float* __restrict__ bias, void* __restrict__ Cout,
    int M, int N, int K) {
  __shared__ u16 As[128 * 32];
  __shared__ u16 Bs[128 * 32];
  const int tid = threadIdx.x;
  const int lane = tid & 63;
  const int wave = tid >> 6;
  const int wr = (wave >> 1) * 64;
  const int wc = (wave & 1) * 64;
  const int c15 = lane & 15;
  const int g = lane >> 4;
  const int bx = blockIdx.x, by = blockIdx.y;

  const u16* gA = A + (size_t)(by * 128 + (tid >> 2)) * K + (tid & 3) * 8;
  const u16* gB = Bm + (size_t)(bx * 128 + (tid >> 2)) * K + (tid & 3) * 8;

  f32x4 acc[4][4];
#pragma unroll
  for (int i = 0; i < 4; ++i)
#pragma unroll
    for (int j = 0; j < 4; ++j) acc[i][j] = (f32x4){0.f, 0.f, 0.f, 0.f};

  for (int k0 = 0; k0 < K; k0 += 32) {
    gload_lds16(gA + k0, &As[wave * 512]);
    gload_lds16(gA + (size_t)64 * K + k0, &As[2048 + wave * 512]);
    gload_lds16(gB + k0, &Bs[wave * 512]);
    gload_lds16(gB + (size_t)64 * K + k0, &Bs[2048 + wave * 512]);
    __syncthreads();
    bf16x8 af[4], bfr[4];
#pragma unroll
    for (int mt = 0; mt < 4; ++mt)
      af[mt] = *(const bf16x8*)&As[(wr + mt * 16 + c15) * 32 + g * 8];
#pragma unroll
    for (int nt = 0; nt < 4; ++nt)
      bfr[nt] = *(const bf16x8*)&Bs[(wc + nt * 16 + c15) * 32 + g * 8];
#pragma unroll
    for (int mt = 0; mt < 4; ++mt)
#pragma unroll
      for (int nt = 0; nt < 4; ++nt)
        acc[mt][nt] = mfma16(af[mt], bfr[nt], acc[mt][nt]);
    __syncthreads();
  }

#pragma unroll
  for (int mt = 0; mt < 4; ++mt)
#pragma unroll
    for (int nt = 0; nt < 4; ++nt) {
      const int m = by * 128 + wr + mt * 16 + g * 4;
      const int n = bx * 128 + wc + nt * 16 + c15;
      const float bv = bias[n];
#pragma unroll
      for (int r = 0; r < 4; ++r) {
        const float v = acc[mt][nt][r] + bv;
        if (OUT_BF16)
          ((u16*)Cout)[(size_t)(m + r) * N + n] = f2bf(v);
        else
          ((float*)Cout)[(size_t)(m + r) * N + n] = v;
      }
    }
}

// ---- big GEMM: 256^2 tile, 4 FAT waves (128x128 each, mfma32) ------------
// LDS-read traffic cut 96 -> 64 b128 per tile per CU (wave perimeter 256 vs
// 192 rows but 4 waves not 8): LDS pipe 1280 cy/tile vs MFMA 1033 -> even
// serialized beats the 8-wave layout; overlap upside to ~35us. 1 wave/SIMD
// (acc 4x4xf32x16 = 256 VGPR; ~350 total, no spill). Protocol = R11-verified:
// 4 rotating buffers, stage t+2, one vmcnt(8)+FENCED_BARRIER per tile.
// WAR: buf[(t+2)&3] reads retired before barrier(t-2), two barriers ago.
// RAW: vmcnt(8) retires exactly tile t+1's 8 loads (in-order); vmcnt(0) tail.
// Swizzle: 16B-chunk ^ ((row>>1)&3), both sides (measured conflict-free).
// mfma32 frags (attn-verified): A row=l31, k=hi*8+j; C/D col=l31,
// row=(r&3)+8*(r>>2)+4*hi.
template <bool OUT_BF16>
__global__ __launch_bounds__(256, 1) void gemm_fat(
    const u16* __restrict__ A, const u16* __restrict__ Bm,
    const float* __restrict__ bias, void* __restrict__ Cout,
    int M, int N, int K) {
  extern __shared__ u16 lds[];          // 4 bufs x (A 8192 + B 8192) u16
  const int tid = threadIdx.x;
  const int lane = tid & 63, wave = tid >> 6;
  const int wm = wave >> 1, wn = wave & 1;
  const int l31 = lane & 31, hi = lane >> 5;
  const int bid = blockIdx.y * gridDim.x + blockIdx.x;
  const int sw = (bid & 7) * 32 + (bid >> 3);   // XCD-contiguous, bijective
  const int bn = sw & 7, bm = sw >> 3;
  const int NT = K >> 5;

  // staging: 8 gloads/thread/tile (4 A + 4 B); chunk c = (i*4+wave)*64+lane
  // covers LDS linearly (byte c*16); source chunk pre-swizzled ^((row>>1)&3).
  const u16* pA[4]; const u16* pB[4];
  int dj[4];
#pragma unroll
  for (int i = 0; i < 4; ++i) {
    const int c = (i * 4 + wave) * 64 + lane;
    const int row = c >> 2;
    const int sx = (c & 3) ^ ((row >> 1) & 3);
    pA[i] = A + (size_t)(bm * 256 + row) * K + sx * 8;
    pB[i] = Bm + (size_t)(bn * 256 + row) * K + sx * 8;
    dj[i] = (i * 4 + wave) * 512;
  }

  // ds_read offsets (u16): row r = w*128 + f*32 + l31 (f folds into imm);
  // slot = (kh*16 + hi*8) ^ (((l31>>1)&3)<<3); kh flips bit4 -> ^16.
  const int swz3 = ((l31 >> 1) & 3) << 3;
  const int aoff0 = (wm * 128 + l31) * 32 + ((hi * 8) ^ swz3);
  const int aoff1 = aoff0 ^ 16;
  const int boff0 = 8192 + (wn * 128 + l31) * 32 + ((hi * 8) ^ swz3);
  const int boff1 = boff0 ^ 16;

  f32x16 acc[4][4];
#pragma unroll
  for (int i = 0; i < 4; ++i)
#pragma unroll
    for (int j = 0; j < 4; ++j)
#pragma unroll
      for (int r = 0; r < 16; ++r) acc[i][j][r] = 0.f;

  // prologue: tile0 -> buf0, tile1 -> buf1; retire tile0 (oldest 8)
#pragma unroll
  for (int i = 0; i < 4; ++i) { gload_lds16(pA[i], lds + dj[i]);
                                gload_lds16(pB[i], lds + 8192 + dj[i]); }
#pragma unroll
  for (int i = 0; i < 4; ++i) { pA[i] += 32; pB[i] += 32; }
#pragma unroll
  for (int i = 0; i < 4; ++i) { gload_lds16(pA[i], lds + 16384 + dj[i]);
                                gload_lds16(pB[i], lds + 24576 + dj[i]); }
#pragma unroll
  for (int i = 0; i < 4; ++i) { pA[i] += 32; pB[i] += 32; }
  asm volatile("s_waitcnt vmcnt(8)" ::: "memory");
  FENCED_BARRIER();

  for (int t = 0; t < NT; ++t) {
    const bool more = (t + 2 < NT);
    const u16* cb = lds + (t & 3) * 16384;
    u16* sb = lds + ((t + 2) & 3) * 16384;

    bf16x8 a0[4], a1[4], b0[4], b1[4];
#pragma unroll
    for (int f = 0; f < 4; ++f) {
      a0[f] = *(const bf16x8*)(cb + aoff0 + f * 1024);
      a1[f] = *(const bf16x8*)(cb + aoff1 + f * 1024);
      b0[f] = *(const bf16x8*)(cb + boff0 + f * 1024);
      b1[f] = *(const bf16x8*)(cb + boff1 + f * 1024);
    }

    if (more) {
#pragma unroll
      for (int i = 0; i < 4; ++i) { gload_lds16(pA[i], sb + dj[i]);
                                    gload_lds16(pB[i], sb + 8192 + dj[i]); }
#pragma unroll
      for (int i = 0; i < 4; ++i) { pA[i] += 32; pB[i] += 32; }
    }

    __builtin_amdgcn_s_setprio(1);
#pragma unroll
    for (int fa = 0; fa < 4; ++fa)
#pragma unroll
      for (int fb = 0; fb < 4; ++fb)
        acc[fa][fb] = mfma32(a0[fa], b0[fb], acc[fa][fb]);
#pragma unroll
    for (int fa = 0; fa < 4; ++fa)
#pragma unroll
      for (int fb = 0; fb < 4; ++fb)
        acc[fa][fb] = mfma32(a1[fa], b1[fb], acc[fa][fb]);
    __builtin_amdgcn_s_setprio(0);

    if (more) asm volatile("s_waitcnt vmcnt(8)" ::: "memory");
    else      asm volatile("s_waitcnt vmcnt(0)" ::: "memory");
    FENCED_BARRIER();
  }

  // epilogue: C row m = (r&3)+8*(r>>2)+4*hi (per reg), col n = l31
#pragma unroll
  for (int fa = 0; fa < 4; ++fa)
#pragma unroll
    for (int fb = 0; fb < 4; ++fb) {
      const int n = bn * 256 + wn * 128 + fb * 32 + l31;
      const float bv = bias[n];
#pragma unroll
      for (int r = 0; r < 16; ++r) {
        const int m = bm * 256 + wm * 128 + fa * 32 +
                      (r & 3) + 8 * (r >> 2) + 4 * hi;
        const float v = acc[fa][fb][r] + bv;
        if (OUT_BF16)
          ((u16*)Cout)[(size_t)m * N + n] = f2bf(v);
        else
          ((float*)Cout)[(size_t)m * N + n] = v;
      }
    }
}

// ---------------- V transpose: (B,S,H,D) -> (B,H,D,S) ----------------
__global__ __launch_bounds__(256) void transpose_v(const u16* __restrict__ v,
                                                   u16* __restrict__ vt) {
  __shared__ u16 tile[32][36];
  const int s0 = blockIdx.x * 32;
  const int bh = blockIdx.y;
  const int d0 = blockIdx.z * 32;
  const int b = bh >> 4, h = bh & 15;
  const int tid = threadIdx.x;
  const int sl = tid >> 3, dl = (tid & 7) * 4;
  us4 val = *(const us4*)(v + (size_t)(b * S_ + s0 + sl) * HID_ + h * HD_ + d0 + dl);
  *(us4*)&tile[sl][dl] = val;
  __syncthreads();
  const int dl2 = tid >> 3, sl2 = (tid & 7) * 4;
  us4 outv = { tile[sl2 + 0][dl2], tile[sl2 + 1][dl2],
               tile[sl2 + 2][dl2], tile[sl2 + 3][dl2] };
  *(us4*)(vt + ((size_t)bh * HD_ + d0 + dl2) * S_ + s0 + sl2) = outv;
}

// ---------------- fused masked cross-attention, 32x32 MFMA ----------------
// (unchanged from R12: 4 rotating K/V buffers + counted vmcnt(4) + fenced
// barrier per iteration; decorrelated V swizzle; QK accumulator split.)
__global__ __launch_bounds__(256) void attn_fwd(
    const u16* __restrict__ q, const u16* __restrict__ k,
    const u16* __restrict__ vt, const int* __restrict__ mask,
    const float* __restrict__ gate, u16* __restrict__ ctx) {
  __shared__ u16 smem[32768];   // [0,16384): K bufs x4; [16384,32768): V bufs x4
  __shared__ float addend[S_];
  const int tid = threadIdx.x, lane = tid & 63, wave = tid >> 6;
  const int bh = blockIdx.y, b = bh >> 4, h = bh & 15;
  const int tw = blockIdx.x * 128 + wave * 32;
  const int l31 = lane & 31, hi = lane >> 5;

  const u16* kb  = k + (size_t)b * S_ * HID_ + h * HD_;
  const u16* vtb = vt + (size_t)bh * HD_ * S_;

  const u16* sp[4];
  int dj[4];
  u16* ldsbase;
  ptrdiff_t stride;
  if (wave < 2) {
    ldsbase = smem;                       // K: 32 s-rows x 256B per chunk
    stride = 32 * HID_;
#pragma unroll
    for (int i = 0; i < 4; ++i) {
      const int jj = wave * 4 + i;
      const int row = jj * 4 + (lane >> 4);
      const int cb = (lane & 15) * 16;
      const int cbp = cb ^ ((row & 7) << 4);
      sp[i] = kb + (size_t)row * HID_ + (cbp >> 1);
      dj[i] = jj * 512;
    }
  } else {
    ldsbase = smem + 16384;               // V^T: 128 d-rows x 64B per chunk
    stride = 32;
#pragma unroll
    for (int i = 0; i < 4; ++i) {
      const int jj = (wave - 2) * 4 + i;
      const int d = jj * 16 + (lane >> 2);
      const int cb = (lane & 3) * 16;
      const int cbp = cb ^ (((d >> 1) & 3) << 4);   // decorrelated swizzle
      sp[i] = vtb + (size_t)d * S_ + (cbp >> 1);
      dj[i] = jj * 512;
    }
  }
#define STAGE(cur)                                            \
  do {                                                        \
    _Pragma("unroll") for (int i_ = 0; i_ < 4; ++i_) {        \
      gload_lds16(sp[i_], ldsbase + (cur) * 4096 + dj[i_]);   \
      sp[i_] += stride;                                       \
    }                                                         \
  } while (0)

  for (int s = tid; s < S_; s += 256)
    addend[s] = mask[b * S_ + s] ? 0.f : -1e30f;

  const u16* qrow = q + (size_t)(b * T_ + tw + l31) * HID_ + h * HD_;
  bf16x8 qf[8];
#pragma unroll
  for (int dc = 0; dc < 8; ++dc)
    qf[dc] = *(const bf16x8*)&qrow[dc * 16 + hi * 8];

  STAGE(0);
  STAGE(1);

  int kofs[8];
#pragma unroll
  for (int dc = 0; dc < 8; ++dc)
    kofs[dc] = l31 * 128 + (((dc * 32 + hi * 16) ^ ((l31 & 7) << 4)) >> 1);
  const int vswz = ((l31 >> 1) & 3) << 4;               // matches staging
  const int vcol0 = ((hi * 16) ^ vswz) >> 1;
  const int vcol1 = ((32 + hi * 16) ^ vswz) >> 1;

  float m_run = -1e30f, l_run = 0.f;
  f32x16 ct[4];
#pragma unroll
  for (int i = 0; i < 4; ++i)
#pragma unroll
    for (int r = 0; r < 16; ++r) ct[i][r] = 0.f;
  const float scale = 0.08838834764831845f;  // 1/sqrt(128)

  asm volatile("s_waitcnt vmcnt(4) lgkmcnt(0)" ::: "memory");
  FENCED_BARRIER();

  for (int it = 0; it < 16; ++it) {
    const int cur = it & 3;
    if (it + 2 < 16) STAGE((it + 2) & 3);
    const int s0 = it * 32;
    const u16* kt = smem + cur * 4096;
    const u16* vl = smem + 16384 + cur * 4096;

    f32x16 st_a, st_b;
#pragma unroll
    for (int r = 0; r < 16; ++r) { st_a[r] = 0.f; st_b[r] = 0.f; }
    __builtin_amdgcn_s_setprio(1);
#pragma unroll
    for (int dc = 0; dc < 4; ++dc) {
      bf16x8 kf0 = *(const bf16x8*)&kt[kofs[dc]];
      bf16x8 kf1 = *(const bf16x8*)&kt[kofs[4 + dc]];
      st_a = mfma32(kf0, qf[dc], st_a);
      st_b = mfma32(kf1, qf[4 + dc], st_b);
    }
    __builtin_amdgcn_s_setprio(0);

    float sc[16];
#pragma unroll
    for (int rq = 0; rq < 4; ++rq) {
      f4 ad = *(const f4*)&addend[s0 + rq * 8 + hi * 4];
#pragma unroll
      for (int m = 0; m < 4; ++m)
        sc[rq * 4 + m] = (st_a[rq * 4 + m] + st_b[rq * 4 + m]) * scale + ad[m];
    }
    float tm = sc[0];
#pragma unroll
    for (int i = 1; i < 16; ++i) tm = fmaxf(tm, sc[i]);
    tm = fmaxf(tm, __shfl_xor(tm, 32));
    const float nm = fmaxf(m_run, tm);
    if (!__all(nm - m_run <= 8.f)) {   // defer-max (THR=8)
      const float corr = __expf(m_run - nm);
      l_run *= corr;
#pragma unroll
      for (int db = 0; db < 4; ++db)
#pragma unroll
        for (int r = 0; r < 16; ++r) ct[db][r] *= corr;
      m_run = nm;
    }
    float p[16], ps = 0.f;
#pragma unroll
    for (int i = 0; i < 16; ++i) { p[i] = __expf(sc[i] - m_run); ps += p[i]; }
    ps += __shfl_xor(ps, 32);
    l_run += ps;

    u32 w[8], x[8];
#pragma unroll
    for (int q2 = 0; q2 < 4; ++q2) {
      w[2 * q2]     = cvtpk(p[4 * q2],     p[4 * q2 + 1]);
      w[2 * q2 + 1] = cvtpk(p[4 * q2 + 2], p[4 * q2 + 3]);
    }
#pragma unroll
    for (int i = 0; i < 8; ++i) x[i] = __shfl_xor((int)w[i], 32);
    const u32x4 f0 = hi ? (u32x4){x[2], x[3], w[2], w[3]}
                        : (u32x4){w[0], w[1], x[0], x[1]};
    const u32x4 f1 = hi ? (u32x4){x[6], x[7], w[6], w[7]}
                        : (u32x4){w[4], w[5], x[4], x[5]};
    const bf16x8 pf0 = __builtin_bit_cast(bf16x8, f0);
    const bf16x8 pf1 = __builtin_bit_cast(bf16x8, f1);

    __builtin_amdgcn_s_setprio(1);
#pragma unroll
    for (int db = 0; db < 4; ++db) {
      bf16x8 vf0 = *(const bf16x8*)&vl[db * 1024 + l31 * 32 + vcol0];
      ct[db] = mfma32(vf0, pf0, ct[db]);
      bf16x8 vf1 = *(const bf16x8*)&vl[db * 1024 + l31 * 32 + vcol1];
      ct[db] = mfma32(vf1, pf1, ct[db]);
    }
    __builtin_amdgcn_s_setprio(0);

    if (it < 15) {
      if (it < 14) asm volatile("s_waitcnt vmcnt(4)" ::: "memory");
      else         asm volatile("s_waitcnt vmcnt(0)" ::: "memory");
      FENCED_BARRIER();
    }
  }
#undef STAGE

  __syncthreads();   // all waves done with K/V bufs before c_lds aliases them

  const float gsig = 1.f / (1.f + __expf(-gate[0]));
  const float inv = gsig / l_run;
  u16* c_lds = smem + wave * 4352;    // 32 rows x 136 u16
#pragma unroll
  for (int db = 0; db < 4; ++db)
#pragma unroll
    for (int rq = 0; rq < 4; ++rq) {
      us4 o = { f2bf(ct[db][rq * 4 + 0] * inv), f2bf(ct[db][rq * 4 + 1] * inv),
                f2bf(ct[db][rq * 4 + 2] * inv), f2bf(ct[db][rq * 4 + 3] * inv) };
      *(us4*)&c_lds[l31 * 136 + db * 32 + rq * 8 + hi * 4] = o;
    }
  u16* crow = ctx + (size_t)(b * T_ + tw) * HID_ + h * HD_;
#pragma unroll
  for (int rep = 0; rep < 8; ++rep) {
    const int tt = (lane >> 4) + rep * 4;
    us8 valv = *(const us8*)&c_lds[tt * 136 + (lane & 15) * 8];
    *(us8*)&crow[(size_t)tt * HID_ + (lane & 15) * 8] = valv;
  }
}

// ---------------- launch ----------------
extern "C" void kernel_launch(void* const* d_in, const int* in_sizes, int n_in,
                              void* d_out, int out_size, void* d_ws, size_t ws_size,
                              hipStream_t stream) {
  (void)in_sizes; (void)n_in; (void)out_size; (void)ws_size;
  const float* hs   = (const float*)d_in[0];
  const float* nts  = (const float*)d_in[1];
  const int*   mask = (const int*)d_in[2];
  const float* qw   = (const float*)d_in[3];
  const float* qb   = (const float*)d_in[4];
  const float* kw   = (const float*)d_in[5];
  const float* kbi  = (const float*)d_in[6];
  const float* vw   = (const float*)d_in[7];
  const float* vbi  = (const float*)d_in[8];
  const float* ow   = (const float*)d_in[9];
  const float* obi  = (const float*)d_in[10];
  const float* gate = (const float*)d_in[11];
  float* out = (float*)d_out;

  char* w = (char*)d_ws;
  u16* h_bf   = (u16*)(w + 0);          // 33,554,432 B
  u16* n_bf   = (u16*)(w + 33554432);   //  4,194,304 B
  u16* qw_bf  = (u16*)(w + 37748736);   //  8,388,608 B
  u16* kw_bf  = (u16*)(w + 46137344);   //  4,194,304 B
  u16* vw_bf  = (u16*)(w + 50331648);   //  4,194,304 B
  u16* ow_bf  = (u16*)(w + 54525952);   //  8,388,608 B
  u16* q_bf   = (u16*)(w + 62914560);   // 33,554,432 B
  u16* k_bf   = (u16*)(w + 96468992);   //  8,388,608 B
  u16* v_bf   = (u16*)(w + 104857600);  //  8,388,608 B
  u16* vt_bf  = (u16*)(w + 113246208);  //  8,388,608 B  (end 121,634,816)
  u16* ctx_bf = h_bf;                   // alias: hidden_bf16 dead after Q-proj

  hipFuncSetAttribute(reinterpret_cast<const void*>(&gemm_fat<true>),
                      hipFuncAttributeMaxDynamicSharedMemorySize, 131072);
  hipFuncSetAttribute(reinterpret_cast<const void*>(&gemm_fat<false>),
                      hipFuncAttributeMaxDynamicSharedMemorySize, 131072);

  convert_all<<<dim3(2048), dim3(256), 0, stream>>>(
      hs, nts, qw, kw, vw, ow, h_bf, n_bf, qw_bf, kw_bf, vw_bf, ow_bf);
  gemm_bt<true><<<dim3(16, 16), dim3(256), 0, stream>>>(
      n_bf, kw_bf, kbi, k_bf, 2048, 2048, 1024);
  gemm_bt<true><<<dim3(16, 16), dim3(256), 0, stream>>>(
      n_bf, vw_bf, vbi, v_bf, 2048, 2048, 1024);
  transpose_v<<<dim3(16, 64, 4), dim3(256), 0, stream>>>(v_bf, vt_bf);
  // Q projection: M=8192, N=2048, K=2048 — grid 8x32 = 256 blocks (1/CU)
  gemm_fat<true><<<dim3(8, 32), dim3(256), 131072, stream>>>(
      h_bf, qw_bf, qb, q_bf, 8192, 2048, 2048);
  attn_fwd<<<dim3(16, 64), dim3(256), 0, stream>>>(
      q_bf, k_bf, vt_bf, mask, gate, ctx_bf);
  // Output projection -> fp32 d_out
  gemm_fat<false><<<dim3(8, 32), dim3(256), 131072, stream>>>(
      ctx_bf, ow_bf, obi, out, 8192, 2048, 2048);
}

// Round 14
// 258.833 us; speedup vs baseline: 1.1453x; 1.1453x over previous
//
#include <hip/hip_runtime.h>
#include <hip/hip_bf16.h>
#include <stdint.h>

#define B_ 4
#define T_ 2048
#define S_ 512
#define HID_ 2048
#define ND_ 1024
#define NH_ 16
#define HD_ 128

typedef unsigned short u16;
typedef unsigned int u32;
typedef __attribute__((ext_vector_type(8))) short bf16x8;
typedef __attribute__((ext_vector_type(4))) float f32x4;
typedef __attribute__((ext_vector_type(16))) float f32x16;
typedef __attribute__((ext_vector_type(4))) float f4;
typedef __attribute__((ext_vector_type(4))) u16 us4;
typedef __attribute__((ext_vector_type(8))) u16 us8;
typedef __attribute__((ext_vector_type(4))) u32 u32x4;

__device__ inline u16 f2bf(float f) {
  unsigned u = __builtin_bit_cast(unsigned, f);
  u += 0x7FFFu + ((u >> 16) & 1u);   // round-to-nearest-even
  return (u16)(u >> 16);
}

__device__ inline u32 cvtpk(float lo, float hi) {   // bf16(lo) | bf16(hi)<<16
  u32 r;
  asm("v_cvt_pk_bf16_f32 %0, %1, %2" : "=v"(r) : "v"(lo), "v"(hi));
  return r;
}

__device__ inline f32x4 mfma16(bf16x8 a, bf16x8 b, f32x4 c) {
  return __builtin_amdgcn_mfma_f32_16x16x32_bf16(a, b, c, 0, 0, 0);
}
__device__ inline f32x16 mfma32(bf16x8 a, bf16x8 b, f32x16 c) {
  return __builtin_amdgcn_mfma_f32_32x32x16_bf16(a, b, c, 0, 0, 0);
}

__device__ inline void gload_lds16(const u16* g, u16* l) {
  __builtin_amdgcn_global_load_lds(
      (const __attribute__((address_space(1))) unsigned int*)g,
      (__attribute__((address_space(3))) unsigned int*)l, 16, 0, 0);
}

// fenced barrier: s_barrier that is ALSO a compiler memory fence (R10 race fix)
#define FENCED_BARRIER() asm volatile("s_barrier" ::: "memory")

// ---------------- fp32 -> bf16 conversion for all operands ----------------
__global__ __launch_bounds__(256) void convert_all(
    const float* __restrict__ h, const float* __restrict__ n,
    const float* __restrict__ qw, const float* __restrict__ kw,
    const float* __restrict__ vw, const float* __restrict__ ow,
    u16* __restrict__ dh, u16* __restrict__ dn, u16* __restrict__ dqw,
    u16* __restrict__ dkw, u16* __restrict__ dvw, u16* __restrict__ dow) {
  const int C0 = 4194304;            // hidden 16.78M
  const int C1 = C0 + 524288;        // notes 2.10M
  const int C2 = C1 + 1048576;       // q_w 4.19M
  const int C3 = C2 + 524288;        // k_w 2.10M
  const int C4 = C3 + 524288;        // v_w 2.10M
  const int C5 = C4 + 1048576;       // o_w 4.19M
  for (int c = blockIdx.x * blockDim.x + threadIdx.x; c < C5;
       c += gridDim.x * blockDim.x) {
    const float* s; u16* d; int o;
    if (c < C0)      { s = h;  d = dh;  o = c; }
    else if (c < C1) { s = n;  d = dn;  o = c - C0; }
    else if (c < C2) { s = qw; d = dqw; o = c - C1; }
    else if (c < C3) { s = kw; d = dkw; o = c - C2; }
    else if (c < C4) { s = vw; d = dvw; o = c - C3; }
    else             { s = ow; d = dow; o = c - C4; }
    f4 v = ((const f4*)s)[o];
    us4 r = { f2bf(v[0]), f2bf(v[1]), f2bf(v[2]), f2bf(v[3]) };
    ((us4*)d)[o] = r;
  }
}

// ------- merged K/V projection GEMM (128^2 tile, m97 structure) -----------
// blockIdx.z selects {k_w->k_out} or {v_w->v_out}; both read notes_bf.
// Grid 512 blocks = 2 blocks/CU -> the two projections co-schedule.
__global__ __launch_bounds__(256) void gemm_kv(
    const u16* __restrict__ A,
    const u16* __restrict__ B0, const float* __restrict__ bias0,
    u16* __restrict__ C0v,
    const u16* __restrict__ B1, const float* __restrict__ bias1,
    u16* __restrict__ C1v, int M, int N, int K) {
  const u16* Bm = blockIdx.z ? B1 : B0;
  const float* bias = blockIdx.z ? bias1 : bias0;
  u16* Cout = blockIdx.z ? C1v : C0v;

  __shared__ u16 As[128 * 32];
  __shared__ u16 Bs[128 * 32];
  const int tid = threadIdx.x;
  const int lane = tid & 63;
  const int wave = tid >> 6;
  const int wr = (wave >> 1) * 64;
  const int wc = (wave & 1) * 64;
  const int c15 = lane & 15;
  const int g = lane >> 4;
  const int bx = blockIdx.x, by = blockIdx.y;

  const u16* gA = A + (size_t)(by * 128 + (tid >> 2)) * K + (tid & 3) * 8;
  const u16* gB = Bm + (size_t)(bx * 128 + (tid >> 2)) * K + (tid & 3) * 8;

  f32x4 acc[4][4];
#pragma unroll
  for (int i = 0; i < 4; ++i)
#pragma unroll
    for (int j = 0; j < 4; ++j) acc[i][j] = (f32x4){0.f, 0.f, 0.f, 0.f};

  for (int k0 = 0; k0 < K; k0 += 32) {
    gload_lds16(gA + k0, &As[wave * 512]);
    gload_lds16(gA + (size_t)64 * K + k0, &As[2048 + wave * 512]);
    gload_lds16(gB + k0, &Bs[wave * 512]);
    gload_lds16(gB + (size_t)64 * K + k0, &Bs[2048 + wave * 512]);
    __syncthreads();
    bf16x8 af[4], bfr[4];
#pragma unroll
    for (int mt = 0; mt < 4; ++mt)
      af[mt] = *(const bf16x8*)&As[(wr + mt * 16 + c15) * 32 + g * 8];
#pragma unroll
    for (int nt = 0; nt < 4; ++nt)
      bfr[nt] = *(const bf16x8*)&Bs[(wc + nt * 16 + c15) * 32 + g * 8];
#pragma unroll
    for (int mt = 0; mt < 4; ++mt)
#pragma unroll
      for (int nt = 0; nt < 4; ++nt)
        acc[mt][nt] = mfma16(af[mt], bfr[nt], acc[mt][nt]);
    __syncthreads();
  }

#pragma unroll
  for (int mt = 0; mt < 4; ++mt)
#pragma unroll
    for (int nt = 0; nt < 4; ++nt) {
      const int m = by * 128 + wr + mt * 16 + g * 4;
      const int n = bx * 128 + wc + nt * 16 + c15;
      const float bv = bias[n];
#pragma unroll
      for (int r = 0; r < 4; ++r)
        Cout[(size_t)(m + r) * N + n] = f2bf(acc[mt][nt][r] + bv);
    }
}

// ------ big GEMM: 4-phase 256^2 BK=64, deep prefetch, FIXED 3-bit swizzle --
// R9 structure (deep prefetch: tile j+2 staged into live buffer's dead
// regions; boundary vmcnt(8) retires tile j+1, staged a FULL tile earlier).
// Swizzle fix: 128B LDS rows need the full 3-bit row XOR (G4):
//   byte col ^= (row&7)<<4  (row&7 == c15&7 for reads, lane>>3 for staging)
// -> every b128 wave-read spreads 64 lanes over all 8 16B slots = 8 lanes
// per 4-bank group = the 8-cy hardware minimum (R9's 1-bit spread was 4x).
// All barriers fenced (R10). Region-death staging (WAR) + vmcnt rendezvous
// (RAW) arguments unchanged from R9.
template <bool OUT_BF16>
__global__ __launch_bounds__(512, 2) void gemm8p(
    const u16* __restrict__ A, const u16* __restrict__ Bm,
    const float* __restrict__ bias, void* __restrict__ Cout,
    int M, int N, int K) {
  extern __shared__ u16 lds[];          // 2 x 32768 u16 = 128 KB
  const int tid = threadIdx.x;
  const int lane = tid & 63, wave = tid >> 6;
  const int wm = wave >> 2, wn = wave & 3;
  const int c15 = lane & 15, g = lane >> 4;
  const int bid = blockIdx.y * gridDim.x + blockIdx.x;
  const int sw = (bid & 7) * 32 + (bid >> 3);   // XCD-contiguous, bijective
  const int bn = sw & 7, bm = sw >> 3;
  const int NT = K >> 6;                        // BK = 64

  // staging source (pre-swizzled): row = wave*8 + (lane>>3), row&7 = lane>>3;
  // byte col ((lane&7)*16) ^ ((lane>>3)<<4)  [3-bit row swizzle]
  const int r0 = wave * 8 + (lane >> 3);
  const int scol = ((lane & 7) * 16) ^ ((lane >> 3) << 4);
  const size_t dK = (size_t)64 * K;             // +64 rows (2nd sweep)
  const u16* pAlo = A + (size_t)(bm * 256 + r0) * K + (scol >> 1);
  const u16* pAhi = A + (size_t)(bm * 256 + 128 + r0) * K + (scol >> 1);
  const u16* pBlo = Bm + (size_t)(bn * 256 + r0) * K + (scol >> 1);
  const u16* pBhi = Bm + (size_t)(bn * 256 + 128 + r0) * K + (scol >> 1);

#define STG(p, dst)                                  \
  do {                                               \
    gload_lds16((p), (dst) + wave * 512);            \
    gload_lds16((p) + dK, (dst) + 4096 + wave * 512);\
    (p) += 64;                                       \
  } while (0)

  // ds_read cols (u16): (h*32 + g*8) ^ ((c15&7)<<3); frag f at +f*1024
  const int xsw = (c15 & 7) << 3;
  const int colh0 = (g * 8) ^ xsw;
  const int colh1 = (32 + g * 8) ^ xsw;
  const int aoff = wm * 8192 + c15 * 64;
  const int boff = 16384 + (wn >> 1) * 8192 + (wn & 1) * 4096 + c15 * 64;

  f32x4 acc[8][4];
#pragma unroll
  for (int i = 0; i < 8; ++i)
#pragma unroll
    for (int j = 0; j < 4; ++j) acc[i][j] = (f32x4){0.f, 0.f, 0.f, 0.f};

  // prologue: tile0 -> buf0, tile1 -> buf1 (16 loads); retire tile0's 8
  STG(pAlo, lds);
  STG(pAhi, lds + 8192);
  STG(pBlo, lds + 16384);
  STG(pBhi, lds + 24576);
  STG(pAlo, lds + 32768);
  STG(pAhi, lds + 40960);
  STG(pBlo, lds + 49152);
  STG(pBhi, lds + 57344);
  asm volatile("s_waitcnt vmcnt(8)" ::: "memory");
  FENCED_BARRIER();

  for (int j = 0; j < NT; ++j) {
    const int cu = (j & 1) << 15;
    const u16* cb = lds + cu;              // read buffer (tile j)
    u16* rb = lds + cu;                    // stage target = LIVE buffer
    const bool s2 = (j + 2 < NT);

    // ---------------- P1: read A0 + B0; MFMA Q0
    bf16x8 aL[4][2], bL[2][2];
#pragma unroll
    for (int fm = 0; fm < 4; ++fm) {
      aL[fm][0] = *(const bf16x8*)(cb + aoff + fm * 1024 + colh0);
      aL[fm][1] = *(const bf16x8*)(cb + aoff + fm * 1024 + colh1);
    }
#pragma unroll
    for (int fn = 0; fn < 2; ++fn) {
      bL[fn][0] = *(const bf16x8*)(cb + boff + fn * 1024 + colh0);
      bL[fn][1] = *(const bf16x8*)(cb + boff + fn * 1024 + colh1);
    }
    FENCED_BARRIER();
    asm volatile("s_waitcnt lgkmcnt(0)" ::: "memory");
    __builtin_amdgcn_sched_barrier(0);
    __builtin_amdgcn_s_setprio(1);
#pragma unroll
    for (int fm = 0; fm < 4; ++fm)
#pragma unroll
      for (int fn = 0; fn < 2; ++fn) {
        acc[fm][fn] = mfma16(aL[fm][0], bL[fn][0], acc[fm][fn]);
        acc[fm][fn] = mfma16(aL[fm][1], bL[fn][1], acc[fm][fn]);
      }
    __builtin_amdgcn_s_setprio(0);
    FENCED_BARRIER();

    // ---------------- P2: read B1; MFMA Q1
    bf16x8 bH[2][2];
#pragma unroll
    for (int fn = 0; fn < 2; ++fn) {
      bH[fn][0] = *(const bf16x8*)(cb + boff + (2 + fn) * 1024 + colh0);
      bH[fn][1] = *(const bf16x8*)(cb + boff + (2 + fn) * 1024 + colh1);
    }
    FENCED_BARRIER();
    asm volatile("s_waitcnt lgkmcnt(0)" ::: "memory");
    __builtin_amdgcn_sched_barrier(0);
    __builtin_amdgcn_s_setprio(1);
#pragma unroll
    for (int fm = 0; fm < 4; ++fm)
#pragma unroll
      for (int fn = 0; fn < 2; ++fn) {
        acc[fm][2 + fn] = mfma16(aL[fm][0], bH[fn][0], acc[fm][2 + fn]);
        acc[fm][2 + fn] = mfma16(aL[fm][1], bH[fn][1], acc[fm][2 + fn]);
      }
    __builtin_amdgcn_s_setprio(0);
    FENCED_BARRIER();
    // B regions of live buffer now dead (all waves lgkm-drained B reads
    // before arriving at the barrier above).

    // ---------------- P3: read A1; stage B(j+2) into live B regions; Q3
    bf16x8 aH[4][2];
#pragma unroll
    for (int fm = 0; fm < 4; ++fm) {
      aH[fm][0] = *(const bf16x8*)(cb + aoff + (4 + fm) * 1024 + colh0);
      aH[fm][1] = *(const bf16x8*)(cb + aoff + (4 + fm) * 1024 + colh1);
    }
    if (s2) {
      STG(pBlo, rb + 16384);
      STG(pBhi, rb + 24576);
    }
    FENCED_BARRIER();
    asm volatile("s_waitcnt lgkmcnt(0)" ::: "memory");
    __builtin_amdgcn_sched_barrier(0);
    __builtin_amdgcn_s_setprio(1);
#pragma unroll
    for (int fm = 0; fm < 4; ++fm)
#pragma unroll
      for (int fn = 0; fn < 2; ++fn) {
        acc[4 + fm][2 + fn] = mfma16(aH[fm][0], bH[fn][0], acc[4 + fm][2 + fn]);
        acc[4 + fm][2 + fn] = mfma16(aH[fm][1], bH[fn][1], acc[4 + fm][2 + fn]);
      }
    __builtin_amdgcn_s_setprio(0);
    FENCED_BARRIER();
    // A regions now dead.

    // ---------------- P4: stage A(j+2) into live A regions; MFMA Q2
    if (s2) {
      STG(pAlo, rb);
      STG(pAhi, rb + 8192);
    }
    __builtin_amdgcn_s_setprio(1);
#pragma unroll
    for (int fm = 0; fm < 4; ++fm)
#pragma unroll
      for (int fn = 0; fn < 2; ++fn) {
        acc[4 + fm][fn] = mfma16(aH[fm][0], bL[fn][0], acc[4 + fm][fn]);
        acc[4 + fm][fn] = mfma16(aH[fm][1], bL[fn][1], acc[4 + fm][fn]);
      }
    __builtin_amdgcn_s_setprio(0);
    if (j + 1 < NT) {
      if (s2) asm volatile("s_waitcnt vmcnt(8)" ::: "memory");
      else    asm volatile("s_waitcnt vmcnt(0)" ::: "memory");
      FENCED_BARRIER();
    }
  }
#undef STG

  // epilogue: bias + store (C row = g*4+r, col = c15 per fragment)
#pragma unroll
  for (int mf = 0; mf < 8; ++mf)
#pragma unroll
    for (int nf = 0; nf < 4; ++nf) {
      const int m = bm * 256 + wm * 128 + mf * 16 + g * 4;
      const int n = bn * 256 + wn * 64 + nf * 16 + c15;
      const float bv = bias[n];
#pragma unroll
      for (int r = 0; r < 4; ++r) {
        const float v = acc[mf][nf][r] + bv;
        if (OUT_BF16)
          ((u16*)Cout)[(size_t)(m + r) * N + n] = f2bf(v);
        else
          ((float*)Cout)[(size_t)(m + r) * N + n] = v;
      }
    }
}

// ---------------- V transpose: (B,S,H,D) -> (B,H,D,S) ----------------
__global__ __launch_bounds__(256) void transpose_v(const u16* __restrict__ v,
                                                   u16* __restrict__ vt) {
  __shared__ u16 tile[32][36];
  const int s0 = blockIdx.x * 32;
  const int bh = blockIdx.y;
  const int d0 = blockIdx.z * 32;
  const int b = bh >> 4, h = bh & 15;
  const int tid = threadIdx.x;
  const int sl = tid >> 3, dl = (tid & 7) * 4;
  us4 val = *(const us4*)(v + (size_t)(b * S_ + s0 + sl) * HID_ + h * HD_ + d0 + dl);
  *(us4*)&tile[sl][dl] = val;
  __syncthreads();
  const int dl2 = tid >> 3, sl2 = (tid & 7) * 4;
  us4 outv = { tile[sl2 + 0][dl2], tile[sl2 + 1][dl2],
               tile[sl2 + 2][dl2], tile[sl2 + 3][dl2] };
  *(us4*)(vt + ((size_t)bh * HD_ + d0 + dl2) * S_ + s0 + sl2) = outv;
}

// ---------------- fused masked cross-attention, 32x32 MFMA ----------------
// (unchanged from R12: 4 rotating K/V buffers + counted vmcnt(4) + fenced
// barrier per iteration; decorrelated V swizzle; QK accumulator split.)
__global__ __launch_bounds__(256) void attn_fwd(
    const u16* __restrict__ q, const u16* __restrict__ k,
    const u16* __restrict__ vt, const int* __restrict__ mask,
    const float* __restrict__ gate, u16* __restrict__ ctx) {
  __shared__ u16 smem[32768];   // [0,16384): K bufs x4; [16384,32768): V bufs x4
  __shared__ float addend[S_];
  const int tid = threadIdx.x, lane = tid & 63, wave = tid >> 6;
  const int bh = blockIdx.y, b = bh >> 4, h = bh & 15;
  const int tw = blockIdx.x * 128 + wave * 32;
  const int l31 = lane & 31, hi = lane >> 5;

  const u16* kb  = k + (size_t)b * S_ * HID_ + h * HD_;
  const u16* vtb = vt + (size_t)bh * HD_ * S_;

  const u16* sp[4];
  int dj[4];
  u16* ldsbase;
  ptrdiff_t stride;
  if (wave < 2) {
    ldsbase = smem;                       // K: 32 s-rows x 256B per chunk
    stride = 32 * HID_;
#pragma unroll
    for (int i = 0; i < 4; ++i) {
      const int jj = wave * 4 + i;
      const int row = jj * 4 + (lane >> 4);
      const int cb = (lane & 15) * 16;
      const int cbp = cb ^ ((row & 7) << 4);
      sp[i] = kb + (size_t)row * HID_ + (cbp >> 1);
      dj[i] = jj * 512;
    }
  } else {
    ldsbase = smem + 16384;               // V^T: 128 d-rows x 64B per chunk
    stride = 32;
#pragma unroll
    for (int i = 0; i < 4; ++i) {
      const int jj = (wave - 2) * 4 + i;
      const int d = jj * 16 + (lane >> 2);
      const int cb = (lane & 3) * 16;
      const int cbp = cb ^ (((d >> 1) & 3) << 4);   // decorrelated swizzle
      sp[i] = vtb + (size_t)d * S_ + (cbp >> 1);
      dj[i] = jj * 512;
    }
  }
#define STAGE(cur)                                            \
  do {                                                        \
    _Pragma("unroll") for (int i_ = 0; i_ < 4; ++i_) {        \
      gload_lds16(sp[i_], ldsbase + (cur) * 4096 + dj[i_]);   \
      sp[i_] += stride;                                       \
    }                                                         \
  } while (0)

  for (int s = tid; s < S_; s += 256)
    addend[s] = mask[b * S_ + s] ? 0.f : -1e30f;

  const u16* qrow = q + (size_t)(b * T_ + tw + l31) * HID_ + h * HD_;
  bf16x8 qf[8];
#pragma unroll
  for (int dc = 0; dc < 8; ++dc)
    qf[dc] = *(const bf16x8*)&qrow[dc * 16 + hi * 8];

  STAGE(0);
  STAGE(1);

  int kofs[8];
#pragma unroll
  for (int dc = 0; dc < 8; ++dc)
    kofs[dc] = l31 * 128 + (((dc * 32 + hi * 16) ^ ((l31 & 7) << 4)) >> 1);
  const int vswz = ((l31 >> 1) & 3) << 4;               // matches staging
  const int vcol0 = ((hi * 16) ^ vswz) >> 1;
  const int vcol1 = ((32 + hi * 16) ^ vswz) >> 1;

  float m_run = -1e30f, l_run = 0.f;
  f32x16 ct[4];
#pragma unroll
  for (int i = 0; i < 4; ++i)
#pragma unroll
    for (int r = 0; r < 16; ++r) ct[i][r] = 0.f;
  const float scale = 0.08838834764831845f;  // 1/sqrt(128)

  asm volatile("s_waitcnt vmcnt(4) lgkmcnt(0)" ::: "memory");
  FENCED_BARRIER();

  for (int it = 0; it < 16; ++it) {
    const int cur = it & 3;
    if (it + 2 < 16) STAGE((it + 2) & 3);
    const int s0 = it * 32;
    const u16* kt = smem + cur * 4096;
    const u16* vl = smem + 16384 + cur * 4096;

    f32x16 st_a, st_b;
#pragma unroll
    for (int r = 0; r < 16; ++r) { st_a[r] = 0.f; st_b[r] = 0.f; }
    __builtin_amdgcn_s_setprio(1);
#pragma unroll
    for (int dc = 0; dc < 4; ++dc) {
      bf16x8 kf0 = *(const bf16x8*)&kt[kofs[dc]];
      bf16x8 kf1 = *(const bf16x8*)&kt[kofs[4 + dc]];
      st_a = mfma32(kf0, qf[dc], st_a);
      st_b = mfma32(kf1, qf[4 + dc], st_b);
    }
    __builtin_amdgcn_s_setprio(0);

    float sc[16];
#pragma unroll
    for (int rq = 0; rq < 4; ++rq) {
      f4 ad = *(const f4*)&addend[s0 + rq * 8 + hi * 4];
#pragma unroll
      for (int m = 0; m < 4; ++m)
        sc[rq * 4 + m] = (st_a[rq * 4 + m] + st_b[rq * 4 + m]) * scale + ad[m];
    }
    float tm = sc[0];
#pragma unroll
    for (int i = 1; i < 16; ++i) tm = fmaxf(tm, sc[i]);
    tm = fmaxf(tm, __shfl_xor(tm, 32));
    const float nm = fmaxf(m_run, tm);
    if (!__all(nm - m_run <= 8.f)) {   // defer-max (THR=8)
      const float corr = __expf(m_run - nm);
      l_run *= corr;
#pragma unroll
      for (int db = 0; db < 4; ++db)
#pragma unroll
        for (int r = 0; r < 16; ++r) ct[db][r] *= corr;
      m_run = nm;
    }
    float p[16], ps = 0.f;
#pragma unroll
    for (int i = 0; i < 16; ++i) { p[i] = __expf(sc[i] - m_run); ps += p[i]; }
    ps += __shfl_xor(ps, 32);
    l_run += ps;

    u32 w[8], x[8];
#pragma unroll
    for (int q2 = 0; q2 < 4; ++q2) {
      w[2 * q2]     = cvtpk(p[4 * q2],     p[4 * q2 + 1]);
      w[2 * q2 + 1] = cvtpk(p[4 * q2 + 2], p[4 * q2 + 3]);
    }
#pragma unroll
    for (int i = 0; i < 8; ++i) x[i] = __shfl_xor((int)w[i], 32);
    const u32x4 f0 = hi ? (u32x4){x[2], x[3], w[2], w[3]}
                        : (u32x4){w[0], w[1], x[0], x[1]};
    const u32x4 f1 = hi ? (u32x4){x[6], x[7], w[6], w[7]}
                        : (u32x4){w[4], w[5], x[4], x[5]};
    const bf16x8 pf0 = __builtin_bit_cast(bf16x8, f0);
    const bf16x8 pf1 = __builtin_bit_cast(bf16x8, f1);

    __builtin_amdgcn_s_setprio(1);
#pragma unroll
    for (int db = 0; db < 4; ++db) {
      bf16x8 vf0 = *(const bf16x8*)&vl[db * 1024 + l31 * 32 + vcol0];
      ct[db] = mfma32(vf0, pf0, ct[db]);
      bf16x8 vf1 = *(const bf16x8*)&vl[db * 1024 + l31 * 32 + vcol1];
      ct[db] = mfma32(vf1, pf1, ct[db]);
    }
    __builtin_amdgcn_s_setprio(0);

    if (it < 15) {
      if (it < 14) asm volatile("s_waitcnt vmcnt(4)" ::: "memory");
      else         asm volatile("s_waitcnt vmcnt(0)" ::: "memory");
      FENCED_BARRIER();
    }
  }
#undef STAGE

  __syncthreads();   // all waves done with K/V bufs before c_lds aliases them

  const float gsig = 1.f / (1.f + __expf(-gate[0]));
  const float inv = gsig / l_run;
  u16* c_lds = smem + wave * 4352;    // 32 rows x 136 u16
#pragma unroll
  for (int db = 0; db < 4; ++db)
#pragma unroll
    for (int rq = 0; rq < 4; ++rq) {
      us4 o = { f2bf(ct[db][rq * 4 + 0] * inv), f2bf(ct[db][rq * 4 + 1] * inv),
                f2bf(ct[db][rq * 4 + 2] * inv), f2bf(ct[db][rq * 4 + 3] * inv) };
      *(us4*)&c_lds[l31 * 136 + db * 32 + rq * 8 + hi * 4] = o;
    }
  u16* crow = ctx + (size_t)(b * T_ + tw) * HID_ + h * HD_;
#pragma unroll
  for (int rep = 0; rep < 8; ++rep) {
    const int tt = (lane >> 4) + rep * 4;
    us8 valv = *(const us8*)&c_lds[tt * 136 + (lane & 15) * 8];
    *(us8*)&crow[(size_t)tt * HID_ + (lane & 15) * 8] = valv;
  }
}

// ---------------- launch ----------------
extern "C" void kernel_launch(void* const* d_in, const int* in_sizes, int n_in,
                              void* d_out, int out_size, void* d_ws, size_t ws_size,
                              hipStream_t stream) {
  (void)in_sizes; (void)n_in; (void)out_size; (void)ws_size;
  const float* hs   = (const float*)d_in[0];
  const float* nts  = (const float*)d_in[1];
  const int*   mask = (const int*)d_in[2];
  const float* qw   = (const float*)d_in[3];
  const float* qb   = (const float*)d_in[4];
  const float* kw   = (const float*)d_in[5];
  const float* kbi  = (const float*)d_in[6];
  const float* vw   = (const float*)d_in[7];
  const float* vbi  = (const float*)d_in[8];
  const float* ow   = (const float*)d_in[9];
  const float* obi  = (const float*)d_in[10];
  const float* gate = (const float*)d_in[11];
  float* out = (float*)d_out;

  char* w = (char*)d_ws;
  u16* h_bf   = (u16*)(w + 0);          // 33,554,432 B
  u16* n_bf   = (u16*)(w + 33554432);   //  4,194,304 B
  u16* qw_bf  = (u16*)(w + 37748736);   //  8,388,608 B
  u16* kw_bf  = (u16*)(w + 46137344);   //  4,194,304 B
  u16* vw_bf  = (u16*)(w + 50331648);   //  4,194,304 B
  u16* ow_bf  = (u16*)(w + 54525952);   //  8,388,608 B
  u16* q_bf   = (u16*)(w + 62914560);   // 33,554,432 B
  u16* k_bf   = (u16*)(w + 96468992);   //  8,388,608 B
  u16* v_bf   = (u16*)(w + 104857600);  //  8,388,608 B
  u16* vt_bf  = (u16*)(w + 113246208);  //  8,388,608 B  (end 121,634,816)
  u16* ctx_bf = h_bf;                   // alias: hidden_bf16 dead after Q-proj

  hipFuncSetAttribute(reinterpret_cast<const void*>(&gemm8p<true>),
                      hipFuncAttributeMaxDynamicSharedMemorySize, 131072);
  hipFuncSetAttribute(reinterpret_cast<const void*>(&gemm8p<false>),
                      hipFuncAttributeMaxDynamicSharedMemorySize, 131072);

  convert_all<<<dim3(2048), dim3(256), 0, stream>>>(
      hs, nts, qw, kw, vw, ow, h_bf, n_bf, qw_bf, kw_bf, vw_bf, ow_bf);
  // K and V projections merged: grid 16x16x2 = 512 blocks (2/CU overlap)
  gemm_kv<<<dim3(16, 16, 2), dim3(256), 0, stream>>>(
      n_bf, kw_bf, kbi, k_bf, vw_bf, vbi, v_bf, 2048, 2048, 1024);
  transpose_v<<<dim3(16, 64, 4), dim3(256), 0, stream>>>(v_bf, vt_bf);
  // Q projection: M=8192, N=2048, K=2048 — grid 8x32 = 256 blocks (1/CU)
  gemm8p<true><<<dim3(8, 32), dim3(512), 131072, stream>>>(
      h_bf, qw_bf, qb, q_bf, 8192, 2048, 2048);
  attn_fwd<<<dim3(16, 64), dim3(256), 0, stream>>>(
      q_bf, k_bf, vt_bf, mask, gate, ctx_bf);
  // Output projection -> fp32 d_out
  gemm8p<false><<<dim3(8, 32), dim3(512), 131072, stream>>>(
      ctx_bf, ow_bf, obi, out, 8192, 2048, 2048);
}

// Round 15
// 258.492 us; speedup vs baseline: 1.1468x; 1.0013x over previous
//
#include <hip/hip_runtime.h>
#include <hip/hip_bf16.h>
#include <stdint.h>

#define B_ 4
#define T_ 2048
#define S_ 512
#define HID_ 2048
#define ND_ 1024
#define NH_ 16
#define HD_ 128

typedef unsigned short u16;
typedef unsigned int u32;
typedef __attribute__((ext_vector_type(8))) short bf16x8;
typedef __attribute__((ext_vector_type(4))) float f32x4;
typedef __attribute__((ext_vector_type(16))) float f32x16;
typedef __attribute__((ext_vector_type(4))) float f4;
typedef __attribute__((ext_vector_type(4))) u16 us4;
typedef __attribute__((ext_vector_type(8))) u16 us8;
typedef __attribute__((ext_vector_type(4))) u32 u32x4;

__device__ inline u16 f2bf(float f) {
  unsigned u = __builtin_bit_cast(unsigned, f);
  u += 0x7FFFu + ((u >> 16) & 1u);   // round-to-nearest-even
  return (u16)(u >> 16);
}

__device__ inline u32 cvtpk(float lo, float hi) {   // bf16(lo) | bf16(hi)<<16
  u32 r;
  asm("v_cvt_pk_bf16_f32 %0, %1, %2" : "=v"(r) : "v"(lo), "v"(hi));
  return r;
}

__device__ inline f32x4 mfma16(bf16x8 a, bf16x8 b, f32x4 c) {
  return __builtin_amdgcn_mfma_f32_16x16x32_bf16(a, b, c, 0, 0, 0);
}
__device__ inline f32x16 mfma32(bf16x8 a, bf16x8 b, f32x16 c) {
  return __builtin_amdgcn_mfma_f32_32x32x16_bf16(a, b, c, 0, 0, 0);
}

__device__ inline void gload_lds16(const u16* g, u16* l) {
  __builtin_amdgcn_global_load_lds(
      (const __attribute__((address_space(1))) unsigned int*)g,
      (__attribute__((address_space(3))) unsigned int*)l, 16, 0, 0);
}

// fenced barrier: s_barrier that is ALSO a compiler memory fence (R10 race fix)
#define FENCED_BARRIER() asm volatile("s_barrier" ::: "memory")

// ---------------- fp32 -> bf16 conversion for all operands ----------------
__global__ __launch_bounds__(256) void convert_all(
    const float* __restrict__ h, const float* __restrict__ n,
    const float* __restrict__ qw, const float* __restrict__ kw,
    const float* __restrict__ vw, const float* __restrict__ ow,
    u16* __restrict__ dh, u16* __restrict__ dn, u16* __restrict__ dqw,
    u16* __restrict__ dkw, u16* __restrict__ dvw, u16* __restrict__ dow) {
  const int C0 = 4194304;            // hidden 16.78M
  const int C1 = C0 + 524288;        // notes 2.10M
  const int C2 = C1 + 1048576;       // q_w 4.19M
  const int C3 = C2 + 524288;        // k_w 2.10M
  const int C4 = C3 + 524288;        // v_w 2.10M
  const int C5 = C4 + 1048576;       // o_w 4.19M
  for (int c = blockIdx.x * blockDim.x + threadIdx.x; c < C5;
       c += gridDim.x * blockDim.x) {
    const float* s; u16* d; int o;
    if (c < C0)      { s = h;  d = dh;  o = c; }
    else if (c < C1) { s = n;  d = dn;  o = c - C0; }
    else if (c < C2) { s = qw; d = dqw; o = c - C1; }
    else if (c < C3) { s = kw; d = dkw; o = c - C2; }
    else if (c < C4) { s = vw; d = dvw; o = c - C3; }
    else             { s = ow; d = dow; o = c - C4; }
    f4 v = ((const f4*)s)[o];
    us4 r = { f2bf(v[0]), f2bf(v[1]), f2bf(v[2]), f2bf(v[3]) };
    ((us4*)d)[o] = r;
  }
}

// ------- merged K/V projection GEMM (128^2 tile, m97 structure) -----------
// blockIdx.z == 0: K-proj -> k_bf row-major (B*S, HID).
// blockIdx.z == 1: V-proj -> vt DIRECTLY TRANSPOSED (B,H,D,S): the C
// fragment's 4 consecutive rows are 4 consecutive s at fixed d -> 8B us4
// store (better vectorized than the old row-major 4x2B scatter). Deletes
// the transpose_v kernel and the v_bf round-trip.
__global__ __launch_bounds__(256) void gemm_kv(
    const u16* __restrict__ A,
    const u16* __restrict__ B0, const float* __restrict__ bias0,
    u16* __restrict__ Ck,
    const u16* __restrict__ B1, const float* __restrict__ bias1,
    u16* __restrict__ Cvt, int M, int N, int K) {
  const int zi = blockIdx.z;
  const u16* Bm = zi ? B1 : B0;
  const float* bias = zi ? bias1 : bias0;

  __shared__ u16 As[128 * 32];
  __shared__ u16 Bs[128 * 32];
  const int tid = threadIdx.x;
  const int lane = tid & 63;
  const int wave = tid >> 6;
  const int wr = (wave >> 1) * 64;
  const int wc = (wave & 1) * 64;
  const int c15 = lane & 15;
  const int g = lane >> 4;
  const int bx = blockIdx.x, by = blockIdx.y;

  const u16* gA = A + (size_t)(by * 128 + (tid >> 2)) * K + (tid & 3) * 8;
  const u16* gB = Bm + (size_t)(bx * 128 + (tid >> 2)) * K + (tid & 3) * 8;

  f32x4 acc[4][4];
#pragma unroll
  for (int i = 0; i < 4; ++i)
#pragma unroll
    for (int j = 0; j < 4; ++j) acc[i][j] = (f32x4){0.f, 0.f, 0.f, 0.f};

  for (int k0 = 0; k0 < K; k0 += 32) {
    gload_lds16(gA + k0, &As[wave * 512]);
    gload_lds16(gA + (size_t)64 * K + k0, &As[2048 + wave * 512]);
    gload_lds16(gB + k0, &Bs[wave * 512]);
    gload_lds16(gB + (size_t)64 * K + k0, &Bs[2048 + wave * 512]);
    __syncthreads();
    bf16x8 af[4], bfr[4];
#pragma unroll
    for (int mt = 0; mt < 4; ++mt)
      af[mt] = *(const bf16x8*)&As[(wr + mt * 16 + c15) * 32 + g * 8];
#pragma unroll
    for (int nt = 0; nt < 4; ++nt)
      bfr[nt] = *(const bf16x8*)&Bs[(wc + nt * 16 + c15) * 32 + g * 8];
#pragma unroll
    for (int mt = 0; mt < 4; ++mt)
#pragma unroll
      for (int nt = 0; nt < 4; ++nt)
        acc[mt][nt] = mfma16(af[mt], bfr[nt], acc[mt][nt]);
    __syncthreads();
  }

#pragma unroll
  for (int mt = 0; mt < 4; ++mt)
#pragma unroll
    for (int nt = 0; nt < 4; ++nt) {
      const int m = by * 128 + wr + mt * 16 + g * 4;
      const int n = bx * 128 + wc + nt * 16 + c15;
      const float bv = bias[n];
      if (zi == 0) {
#pragma unroll
        for (int r = 0; r < 4; ++r)
          Ck[(size_t)(m + r) * N + n] = f2bf(acc[mt][nt][r] + bv);
      } else {
        // transposed V store: b = m>>9 (const over r), s = (m&511)+r,
        // h = n>>7, d = n&127 -> vt[((b*16+h)*128+d)*512 + s], 8B aligned
        const int b = m >> 9, s = m & 511;
        const int hh = n >> 7, d = n & 127;
        us4 o = { f2bf(acc[mt][nt][0] + bv), f2bf(acc[mt][nt][1] + bv),
                  f2bf(acc[mt][nt][2] + bv), f2bf(acc[mt][nt][3] + bv) };
        *(us4*)&Cvt[((size_t)(b * 16 + hh) * 128 + d) * 512 + s] = o;
      }
    }
}

// ---- big GEMM: 256^2 tile, 4-buffer, ONE fenced barrier + counted vmcnt ---
// (exact R11 structure — best measured: 69.5 us, MfmaUtil 40.6%, conflicts 0;
// beats every phase-split variant tried in R7-R14)
template <bool OUT_BF16>
__global__ __launch_bounds__(512, 2) void gemm_pipe(
    const u16* __restrict__ A, const u16* __restrict__ Bm,
    const float* __restrict__ bias, void* __restrict__ Cout,
    int M, int N, int K) {
  extern __shared__ u16 lds[];          // 4 bufs x (A 8192 + B 8192) u16
  const int tid = threadIdx.x;
  const int lane = tid & 63, wave = tid >> 6;
  const int wm = wave >> 2, wn = wave & 3;
  const int c15 = lane & 15, g = lane >> 4;
  const int bid = blockIdx.y * gridDim.x + blockIdx.x;
  const int sw = (bid & 7) * 32 + (bid >> 3);   // XCD-contiguous, bijective
  const int bn = sw & 7, bm = sw >> 3;
  const int NT = K >> 5;

  const int srow = tid >> 2;
  const int sx = (tid & 3) ^ ((srow >> 1) & 3);
  const u16* pa0 = A + (size_t)(bm * 256 + srow) * K + sx * 8;
  const u16* pa1 = A + (size_t)(bm * 256 + 128 + srow) * K + sx * 8;
  const u16* pb0 = Bm + (size_t)(bn * 256 + srow) * K + sx * 8;
  const u16* pb1 = Bm + (size_t)(bn * 256 + 128 + srow) * K + sx * 8;

  const int xr = (c15 >> 1) & 3;
  const int aoff = wm * 4096 + c15 * 32 + (g ^ xr) * 8;
  const int boff = 8192 + wn * 2048 + c15 * 32 + (g ^ xr) * 8;

  f32x4 acc[8][4];
#pragma unroll
  for (int i = 0; i < 8; ++i)
#pragma unroll
    for (int j = 0; j < 4; ++j) acc[i][j] = (f32x4){0.f, 0.f, 0.f, 0.f};

  // prologue: tile0 -> buf0, tile1 -> buf1; wait tile0 (retire oldest 4)
  {
    u16* sA = lds + wave * 512;
    u16* sB = lds + 8192 + wave * 512;
    gload_lds16(pa0, sA);          gload_lds16(pa1, sA + 4096);
    gload_lds16(pb0, sB);          gload_lds16(pb1, sB + 4096);
    pa0 += 32; pa1 += 32; pb0 += 32; pb1 += 32;
    gload_lds16(pa0, sA + 16384);  gload_lds16(pa1, sA + 20480);
    gload_lds16(pb0, sB + 16384);  gload_lds16(pb1, sB + 20480);
    pa0 += 32; pa1 += 32; pb0 += 32; pb1 += 32;
  }
  asm volatile("s_waitcnt vmcnt(4)" ::: "memory");
  FENCED_BARRIER();

  for (int t = 0; t < NT; ++t) {
    const bool more = (t + 2 < NT);
    const u16* cb = lds + (t & 3) * 16384;
    u16* sb = lds + ((t + 2) & 3) * 16384;

    bf16x8 a[8], b[4];
#pragma unroll
    for (int mf = 0; mf < 4; ++mf)
      a[mf] = *(const bf16x8*)(cb + aoff + mf * 512);
#pragma unroll
    for (int nf = 0; nf < 4; ++nf)
      b[nf] = *(const bf16x8*)(cb + boff + nf * 512);
#pragma unroll
    for (int mf = 4; mf < 8; ++mf)
      a[mf] = *(const bf16x8*)(cb + aoff + mf * 512);

    if (more) {
      gload_lds16(pa0, sb + wave * 512);
      gload_lds16(pa1, sb + 4096 + wave * 512);
      gload_lds16(pb0, sb + 8192 + wave * 512);
      gload_lds16(pb1, sb + 12288 + wave * 512);
      pa0 += 32; pa1 += 32; pb0 += 32; pb1 += 32;
    }

    __builtin_amdgcn_s_setprio(1);
#pragma unroll
    for (int mf = 0; mf < 8; ++mf)
#pragma unroll
      for (int nf = 0; nf < 4; ++nf)
        acc[mf][nf] = mfma16(a[mf], b[nf], acc[mf][nf]);
    __builtin_amdgcn_s_setprio(0);

    if (more) asm volatile("s_waitcnt vmcnt(4)" ::: "memory");
    else      asm volatile("s_waitcnt vmcnt(0)" ::: "memory");
    FENCED_BARRIER();
  }

  // epilogue: bias + store (C row = g*4+r, col = c15 per fragment)
#pragma unroll
  for (int mf = 0; mf < 8; ++mf)
#pragma unroll
    for (int nf = 0; nf < 4; ++nf) {
      const int m = bm * 256 + wm * 128 + mf * 16 + g * 4;
      const int n = bn * 256 + wn * 64 + nf * 16 + c15;
      const float bv = bias[n];
#pragma unroll
      for (int r = 0; r < 4; ++r) {
        const float v = acc[mf][nf][r] + bv;
        if (OUT_BF16)
          ((u16*)Cout)[(size_t)(m + r) * N + n] = f2bf(v);
        else
          ((float*)Cout)[(size_t)(m + r) * N + n] = v;
      }
    }
}

// ---------------- fused masked cross-attention, 32x32 MFMA ----------------
// (unchanged from R12/R14: 4 rotating K/V buffers + counted vmcnt(4) + fenced
// barrier per iteration; decorrelated V swizzle; QK accumulator split.)
__global__ __launch_bounds__(256) void attn_fwd(
    const u16* __restrict__ q, const u16* __restrict__ k,
    const u16* __restrict__ vt, const int* __restrict__ mask,
    const float* __restrict__ gate, u16* __restrict__ ctx) {
  __shared__ u16 smem[32768];   // [0,16384): K bufs x4; [16384,32768): V bufs x4
  __shared__ float addend[S_];
  const int tid = threadIdx.x, lane = tid & 63, wave = tid >> 6;
  const int bh = blockIdx.y, b = bh >> 4, h = bh & 15;
  const int tw = blockIdx.x * 128 + wave * 32;
  const int l31 = lane & 31, hi = lane >> 5;

  const u16* kb  = k + (size_t)b * S_ * HID_ + h * HD_;
  const u16* vtb = vt + (size_t)bh * HD_ * S_;

  const u16* sp[4];
  int dj[4];
  u16* ldsbase;
  ptrdiff_t stride;
  if (wave < 2) {
    ldsbase = smem;                       // K: 32 s-rows x 256B per chunk
    stride = 32 * HID_;
#pragma unroll
    for (int i = 0; i < 4; ++i) {
      const int jj = wave * 4 + i;
      const int row = jj * 4 + (lane >> 4);
      const int cb = (lane & 15) * 16;
      const int cbp = cb ^ ((row & 7) << 4);
      sp[i] = kb + (size_t)row * HID_ + (cbp >> 1);
      dj[i] = jj * 512;
    }
  } else {
    ldsbase = smem + 16384;               // V^T: 128 d-rows x 64B per chunk
    stride = 32;
#pragma unroll
    for (int i = 0; i < 4; ++i) {
      const int jj = (wave - 2) * 4 + i;
      const int d = jj * 16 + (lane >> 2);
      const int cb = (lane & 3) * 16;
      const int cbp = cb ^ (((d >> 1) & 3) << 4);   // decorrelated swizzle
      sp[i] = vtb + (size_t)d * S_ + (cbp >> 1);
      dj[i] = jj * 512;
    }
  }
#define STAGE(cur)                                            \
  do {                                                        \
    _Pragma("unroll") for (int i_ = 0; i_ < 4; ++i_) {        \
      gload_lds16(sp[i_], ldsbase + (cur) * 4096 + dj[i_]);   \
      sp[i_] += stride;                                       \
    }                                                         \
  } while (0)

  for (int s = tid; s < S_; s += 256)
    addend[s] = mask[b * S_ + s] ? 0.f : -1e30f;

  const u16* qrow = q + (size_t)(b * T_ + tw + l31) * HID_ + h * HD_;
  bf16x8 qf[8];
#pragma unroll
  for (int dc = 0; dc < 8; ++dc)
    qf[dc] = *(const bf16x8*)&qrow[dc * 16 + hi * 8];

  STAGE(0);
  STAGE(1);

  int kofs[8];
#pragma unroll
  for (int dc = 0; dc < 8; ++dc)
    kofs[dc] = l31 * 128 + (((dc * 32 + hi * 16) ^ ((l31 & 7) << 4)) >> 1);
  const int vswz = ((l31 >> 1) & 3) << 4;               // matches staging
  const int vcol0 = ((hi * 16) ^ vswz) >> 1;
  const int vcol1 = ((32 + hi * 16) ^ vswz) >> 1;

  float m_run = -1e30f, l_run = 0.f;
  f32x16 ct[4];
#pragma unroll
  for (int i = 0; i < 4; ++i)
#pragma unroll
    for (int r = 0; r < 16; ++r) ct[i][r] = 0.f;
  const float scale = 0.08838834764831845f;  // 1/sqrt(128)

  asm volatile("s_waitcnt vmcnt(4) lgkmcnt(0)" ::: "memory");
  FENCED_BARRIER();

  for (int it = 0; it < 16; ++it) {
    const int cur = it & 3;
    if (it + 2 < 16) STAGE((it + 2) & 3);
    const int s0 = it * 32;
    const u16* kt = smem + cur * 4096;
    const u16* vl = smem + 16384 + cur * 4096;

    f32x16 st_a, st_b;
#pragma unroll
    for (int r = 0; r < 16; ++r) { st_a[r] = 0.f; st_b[r] = 0.f; }
    __builtin_amdgcn_s_setprio(1);
#pragma unroll
    for (int dc = 0; dc < 4; ++dc) {
      bf16x8 kf0 = *(const bf16x8*)&kt[kofs[dc]];
      bf16x8 kf1 = *(const bf16x8*)&kt[kofs[4 + dc]];
      st_a = mfma32(kf0, qf[dc], st_a);
      st_b = mfma32(kf1, qf[4 + dc], st_b);
    }
    __builtin_amdgcn_s_setprio(0);

    float sc[16];
#pragma unroll
    for (int rq = 0; rq < 4; ++rq) {
      f4 ad = *(const f4*)&addend[s0 + rq * 8 + hi * 4];
#pragma unroll
      for (int m = 0; m < 4; ++m)
        sc[rq * 4 + m] = (st_a[rq * 4 + m] + st_b[rq * 4 + m]) * scale + ad[m];
    }
    float tm = sc[0];
#pragma unroll
    for (int i = 1; i < 16; ++i) tm = fmaxf(tm, sc[i]);
    tm = fmaxf(tm, __shfl_xor(tm, 32));
    const float nm = fmaxf(m_run, tm);
    if (!__all(nm - m_run <= 8.f)) {   // defer-max (THR=8)
      const float corr = __expf(m_run - nm);
      l_run *= corr;
#pragma unroll
      for (int db = 0; db < 4; ++db)
#pragma unroll
        for (int r = 0; r < 16; ++r) ct[db][r] *= corr;
      m_run = nm;
    }
    float p[16], ps = 0.f;
#pragma unroll
    for (int i = 0; i < 16; ++i) { p[i] = __expf(sc[i] - m_run); ps += p[i]; }
    ps += __shfl_xor(ps, 32);
    l_run += ps;

    u32 w[8], x[8];
#pragma unroll
    for (int q2 = 0; q2 < 4; ++q2) {
      w[2 * q2]     = cvtpk(p[4 * q2],     p[4 * q2 + 1]);
      w[2 * q2 + 1] = cvtpk(p[4 * q2 + 2], p[4 * q2 + 3]);
    }
#pragma unroll
    for (int i = 0; i < 8; ++i) x[i] = __shfl_xor((int)w[i], 32);
    const u32x4 f0 = hi ? (u32x4){x[2], x[3], w[2], w[3]}
                        : (u32x4){w[0], w[1], x[0], x[1]};
    const u32x4 f1 = hi ? (u32x4){x[6], x[7], w[6], w[7]}
                        : (u32x4){w[4], w[5], x[4], x[5]};
    const bf16x8 pf0 = __builtin_bit_cast(bf16x8, f0);
    const bf16x8 pf1 = __builtin_bit_cast(bf16x8, f1);

    __builtin_amdgcn_s_setprio(1);
#pragma unroll
    for (int db = 0; db < 4; ++db) {
      bf16x8 vf0 = *(const bf16x8*)&vl[db * 1024 + l31 * 32 + vcol0];
      ct[db] = mfma32(vf0, pf0, ct[db]);
      bf16x8 vf1 = *(const bf16x8*)&vl[db * 1024 + l31 * 32 + vcol1];
      ct[db] = mfma32(vf1, pf1, ct[db]);
    }
    __builtin_amdgcn_s_setprio(0);

    if (it < 15) {
      if (it < 14) asm volatile("s_waitcnt vmcnt(4)" ::: "memory");
      else         asm volatile("s_waitcnt vmcnt(0)" ::: "memory");
      FENCED_BARRIER();
    }
  }
#undef STAGE

  __syncthreads();   // all waves done with K/V bufs before c_lds aliases them

  const float gsig = 1.f / (1.f + __expf(-gate[0]));
  const float inv = gsig / l_run;
  u16* c_lds = smem + wave * 4352;    // 32 rows x 136 u16
#pragma unroll
  for (int db = 0; db < 4; ++db)
#pragma unroll
    for (int rq = 0; rq < 4; ++rq) {
      us4 o = { f2bf(ct[db][rq * 4 + 0] * inv), f2bf(ct[db][rq * 4 + 1] * inv),
                f2bf(ct[db][rq * 4 + 2] * inv), f2bf(ct[db][rq * 4 + 3] * inv) };
      *(us4*)&c_lds[l31 * 136 + db * 32 + rq * 8 + hi * 4] = o;
    }
  u16* crow = ctx + (size_t)(b * T_ + tw) * HID_ + h * HD_;
#pragma unroll
  for (int rep = 0; rep < 8; ++rep) {
    const int tt = (lane >> 4) + rep * 4;
    us8 valv = *(const us8*)&c_lds[tt * 136 + (lane & 15) * 8];
    *(us8*)&crow[(size_t)tt * HID_ + (lane & 15) * 8] = valv;
  }
}

// ---------------- launch ----------------
extern "C" void kernel_launch(void* const* d_in, const int* in_sizes, int n_in,
                              void* d_out, int out_size, void* d_ws, size_t ws_size,
                              hipStream_t stream) {
  (void)in_sizes; (void)n_in; (void)out_size; (void)ws_size;
  const float* hs   = (const float*)d_in[0];
  const float* nts  = (const float*)d_in[1];
  const int*   mask = (const int*)d_in[2];
  const float* qw   = (const float*)d_in[3];
  const float* qb   = (const float*)d_in[4];
  const float* kw   = (const float*)d_in[5];
  const float* kbi  = (const float*)d_in[6];
  const float* vw   = (const float*)d_in[7];
  const float* vbi  = (const float*)d_in[8];
  const float* ow   = (const float*)d_in[9];
  const float* obi  = (const float*)d_in[10];
  const float* gate = (const float*)d_in[11];
  float* out = (float*)d_out;

  char* w = (char*)d_ws;
  u16* h_bf   = (u16*)(w + 0);          // 33,554,432 B
  u16* n_bf   = (u16*)(w + 33554432);   //  4,194,304 B
  u16* qw_bf  = (u16*)(w + 37748736);   //  8,388,608 B
  u16* kw_bf  = (u16*)(w + 46137344);   //  4,194,304 B
  u16* vw_bf  = (u16*)(w + 50331648);   //  4,194,304 B
  u16* ow_bf  = (u16*)(w + 54525952);   //  8,388,608 B
  u16* q_bf   = (u16*)(w + 62914560);   // 33,554,432 B
  u16* k_bf   = (u16*)(w + 96468992);   //  8,388,608 B
  u16* vt_bf  = (u16*)(w + 104857600);  //  8,388,608 B  (end 113,246,208)
  u16* ctx_bf = h_bf;                   // alias: hidden_bf16 dead after Q-proj

  hipFuncSetAttribute(reinterpret_cast<const void*>(&gemm_pipe<true>),
                      hipFuncAttributeMaxDynamicSharedMemorySize, 131072);
  hipFuncSetAttribute(reinterpret_cast<const void*>(&gemm_pipe<false>),
                      hipFuncAttributeMaxDynamicSharedMemorySize, 131072);

  convert_all<<<dim3(2048), dim3(256), 0, stream>>>(
      hs, nts, qw, kw, vw, ow, h_bf, n_bf, qw_bf, kw_bf, vw_bf, ow_bf);
  // K and V projections merged (V written directly transposed)
  gemm_kv<<<dim3(16, 16, 2), dim3(256), 0, stream>>>(
      n_bf, kw_bf, kbi, k_bf, vw_bf, vbi, vt_bf, 2048, 2048, 1024);
  // Q projection: M=8192, N=2048, K=2048 — grid 8x32 = 256 blocks (1/CU)
  gemm_pipe<true><<<dim3(8, 32), dim3(512), 131072, stream>>>(
      h_bf, qw_bf, qb, q_bf, 8192, 2048, 2048);
  attn_fwd<<<dim3(16, 64), dim3(256), 0, stream>>>(
      q_bf, k_bf, vt_bf, mask, gate, ctx_bf);
  // Output projection -> fp32 d_out
  gemm_pipe<false><<<dim3(8, 32), dim3(512), 131072, stream>>>(
      ctx_bf, ow_bf, obi, out, 8192, 2048, 2048);
}